// Round 2
// baseline (353.344 us; speedup 1.0000x reference)
//
#include <hip/hip_runtime.h>

#define NB 8
#define NC 21
#define HW (512 * 512)
#define BLOCKS_PER_SAMPLE 256                    // 1024 pixels per block
#define PIX_PER_BLOCK (HW / BLOCKS_PER_SAMPLE)   // 1024
#define THREADS 256                              // 1 float4 (4 pixels) per thread

// Kernel 1: per-pixel argmax over channels for pred & target, accumulate
// per-block confusion matrix in LDS, flush to global conf with atomics.
// __launch_bounds__(256, 8): 8 waves/SIMD -> VGPR cap 64 -> 32 waves/CU.
__global__ __launch_bounds__(THREADS, 8) void conf_kernel(
    const float* __restrict__ pred,
    const float* __restrict__ targ,
    int* __restrict__ conf /* [NB][NC][NC] */) {
  __shared__ int lconf[NC * NC];
  const int tid = threadIdx.x;
  for (int i = tid; i < NC * NC; i += THREADS) lconf[i] = 0;
  __syncthreads();

  const int b   = blockIdx.x / BLOCKS_PER_SAMPLE;
  const int blk = blockIdx.x % BLOCKS_PER_SAMPLE;
  const float* __restrict__ pbase = pred + (size_t)b * NC * HW;
  const float* __restrict__ tbase = targ + (size_t)b * NC * HW;
  const int p0 = blk * PIX_PER_BLOCK + tid * 4;  // 16B-aligned

  // channel 0 init
  float4 bp = *(const float4*)(pbase + p0);
  float4 bt = *(const float4*)(tbase + p0);
  int ip0 = 0, ip1 = 0, ip2 = 0, ip3 = 0;
  int it0 = 0, it1 = 0, it2 = 0, it3 = 0;
#pragma unroll
  for (int c = 1; c < NC; ++c) {
    float4 vp = *(const float4*)(pbase + (size_t)c * HW + p0);
    float4 vt = *(const float4*)(tbase + (size_t)c * HW + p0);
    if (vp.x > bp.x) { bp.x = vp.x; ip0 = c; }
    if (vp.y > bp.y) { bp.y = vp.y; ip1 = c; }
    if (vp.z > bp.z) { bp.z = vp.z; ip2 = c; }
    if (vp.w > bp.w) { bp.w = vp.w; ip3 = c; }
    if (vt.x > bt.x) { bt.x = vt.x; it0 = c; }
    if (vt.y > bt.y) { bt.y = vt.y; it1 = c; }
    if (vt.z > bt.z) { bt.z = vt.z; it2 = c; }
    if (vt.w > bt.w) { bt.w = vt.w; it3 = c; }
  }
  atomicAdd(&lconf[it0 * NC + ip0], 1);
  atomicAdd(&lconf[it1 * NC + ip1], 1);
  atomicAdd(&lconf[it2 * NC + ip2], 1);
  atomicAdd(&lconf[it3 * NC + ip3], 1);
  __syncthreads();

  int* __restrict__ gconf = conf + b * NC * NC;
  for (int i = tid; i < NC * NC; i += THREADS) {
    int v = lconf[i];
    if (v) atomicAdd(&gconf[i], v);
  }
}

// Kernel 2: conf -> per-class IoU -> per-sample mean over valid classes ->
// batch mean scalar.
__global__ __launch_bounds__(256) void iou_kernel(const int* __restrict__ conf,
                                                  float* __restrict__ out) {
  __shared__ float iou_sum[NB];
  __shared__ int valid_cnt[NB];
  const int tid = threadIdx.x;
  if (tid < NB) { iou_sum[tid] = 0.f; valid_cnt[tid] = 0; }
  __syncthreads();

  if (tid < NB * NC) {
    const int b = tid / NC, c = tid % NC;
    const int* __restrict__ m = conf + b * NC * NC;
    const int tp = m[c * NC + c];
    int row = 0, col = 0;
#pragma unroll
    for (int j = 0; j < NC; ++j) {
      row += m[c * NC + j];  // TP + FN
      col += m[j * NC + c];  // TP + FP
    }
    if (tp > 0) {
      const float denom = (float)(row + col - tp);  // TP + FN + FP
      atomicAdd(&iou_sum[b], (float)tp / denom);
      atomicAdd(&valid_cnt[b], 1);
    }
  }
  __syncthreads();

  if (tid == 0) {
    float s = 0.f;
    for (int b = 0; b < NB; ++b) {
      const int n = valid_cnt[b] > 0 ? valid_cnt[b] : 1;
      s += iou_sum[b] / (float)n;
    }
    out[0] = s / (float)NB;
  }
}

extern "C" void kernel_launch(void* const* d_in, const int* in_sizes, int n_in,
                              void* d_out, int out_size, void* d_ws, size_t ws_size,
                              hipStream_t stream) {
  const float* pred = (const float*)d_in[0];
  const float* targ = (const float*)d_in[1];
  float* out = (float*)d_out;
  int* conf = (int*)d_ws;  // NB*NC*NC ints = 14112 B

  hipMemsetAsync(conf, 0, NB * NC * NC * sizeof(int), stream);
  conf_kernel<<<NB * BLOCKS_PER_SAMPLE, THREADS, 0, stream>>>(pred, targ, conf);
  iou_kernel<<<1, 256, 0, stream>>>(conf, out);
}

// Round 3
// 347.953 us; speedup vs baseline: 1.0155x; 1.0155x over previous
//
#include <hip/hip_runtime.h>

#define NB 8
#define NC 21
#define HW (512 * 512)
#define BLOCKS_PER_SAMPLE 256                    // 1024 pixels per block
#define PIX_PER_BLOCK (HW / BLOCKS_PER_SAMPLE)   // 1024
#define THREADS 256                              // 1 float4 (4 pixels) per thread

// Kernel 1: per-pixel argmax over channels for pred & target, accumulate
// per-block confusion matrix in LDS, flush to global conf with atomics.
// __launch_bounds__(256, 4): VGPR cap 128 -> compiler can keep ~20 of the 42
// independent float4 loads in flight (MLP), at 16 waves/CU residency.
// (256,8) capped VGPR at 32 and serialized the loads -- R2 showed occupancy
// without ILP doesn't help.
__global__ __launch_bounds__(THREADS, 4) void conf_kernel(
    const float* __restrict__ pred,
    const float* __restrict__ targ,
    int* __restrict__ conf /* [NB][NC][NC] */) {
  __shared__ int lconf[NC * NC];
  const int tid = threadIdx.x;
  for (int i = tid; i < NC * NC; i += THREADS) lconf[i] = 0;
  __syncthreads();

  const int b   = blockIdx.x / BLOCKS_PER_SAMPLE;
  const int blk = blockIdx.x % BLOCKS_PER_SAMPLE;
  const float* __restrict__ pbase = pred + (size_t)b * NC * HW;
  const float* __restrict__ tbase = targ + (size_t)b * NC * HW;
  const int p0 = blk * PIX_PER_BLOCK + tid * 4;  // 16B-aligned

  // channel 0 init
  float4 bp = *(const float4*)(pbase + p0);
  float4 bt = *(const float4*)(tbase + p0);
  int ip0 = 0, ip1 = 0, ip2 = 0, ip3 = 0;
  int it0 = 0, it1 = 0, it2 = 0, it3 = 0;
#pragma unroll
  for (int c = 1; c < NC; ++c) {
    float4 vp = *(const float4*)(pbase + (size_t)c * HW + p0);
    float4 vt = *(const float4*)(tbase + (size_t)c * HW + p0);
    if (vp.x > bp.x) { bp.x = vp.x; ip0 = c; }
    if (vp.y > bp.y) { bp.y = vp.y; ip1 = c; }
    if (vp.z > bp.z) { bp.z = vp.z; ip2 = c; }
    if (vp.w > bp.w) { bp.w = vp.w; ip3 = c; }
    if (vt.x > bt.x) { bt.x = vt.x; it0 = c; }
    if (vt.y > bt.y) { bt.y = vt.y; it1 = c; }
    if (vt.z > bt.z) { bt.z = vt.z; it2 = c; }
    if (vt.w > bt.w) { bt.w = vt.w; it3 = c; }
  }
  atomicAdd(&lconf[it0 * NC + ip0], 1);
  atomicAdd(&lconf[it1 * NC + ip1], 1);
  atomicAdd(&lconf[it2 * NC + ip2], 1);
  atomicAdd(&lconf[it3 * NC + ip3], 1);
  __syncthreads();

  int* __restrict__ gconf = conf + b * NC * NC;
  for (int i = tid; i < NC * NC; i += THREADS) {
    int v = lconf[i];
    if (v) atomicAdd(&gconf[i], v);
  }
}

// Kernel 2: conf -> per-class IoU -> per-sample mean over valid classes ->
// batch mean scalar.
__global__ __launch_bounds__(256) void iou_kernel(const int* __restrict__ conf,
                                                  float* __restrict__ out) {
  __shared__ float iou_sum[NB];
  __shared__ int valid_cnt[NB];
  const int tid = threadIdx.x;
  if (tid < NB) { iou_sum[tid] = 0.f; valid_cnt[tid] = 0; }
  __syncthreads();

  if (tid < NB * NC) {
    const int b = tid / NC, c = tid % NC;
    const int* __restrict__ m = conf + b * NC * NC;
    const int tp = m[c * NC + c];
    int row = 0, col = 0;
#pragma unroll
    for (int j = 0; j < NC; ++j) {
      row += m[c * NC + j];  // TP + FN
      col += m[j * NC + c];  // TP + FP
    }
    if (tp > 0) {
      const float denom = (float)(row + col - tp);  // TP + FN + FP
      atomicAdd(&iou_sum[b], (float)tp / denom);
      atomicAdd(&valid_cnt[b], 1);
    }
  }
  __syncthreads();

  if (tid == 0) {
    float s = 0.f;
    for (int b = 0; b < NB; ++b) {
      const int n = valid_cnt[b] > 0 ? valid_cnt[b] : 1;
      s += iou_sum[b] / (float)n;
    }
    out[0] = s / (float)NB;
  }
}

extern "C" void kernel_launch(void* const* d_in, const int* in_sizes, int n_in,
                              void* d_out, int out_size, void* d_ws, size_t ws_size,
                              hipStream_t stream) {
  const float* pred = (const float*)d_in[0];
  const float* targ = (const float*)d_in[1];
  float* out = (float*)d_out;
  int* conf = (int*)d_ws;  // NB*NC*NC ints = 14112 B

  hipMemsetAsync(conf, 0, NB * NC * NC * sizeof(int), stream);
  conf_kernel<<<NB * BLOCKS_PER_SAMPLE, THREADS, 0, stream>>>(pred, targ, conf);
  iou_kernel<<<1, 256, 0, stream>>>(conf, out);
}